// Round 3
// baseline (692.786 us; speedup 1.0000x reference)
//
#include <hip/hip_runtime.h>

typedef unsigned short u16;
typedef u16   u16x4 __attribute__((ext_vector_type(4)));
typedef u16   u16x8 __attribute__((ext_vector_type(8)));
typedef short s16x8 __attribute__((ext_vector_type(8)));
typedef float f32x4 __attribute__((ext_vector_type(4)));

__device__ __forceinline__ float b2f(u16 u) {
    union { unsigned int i; float f; } v; v.i = ((unsigned int)u) << 16; return v.f;
}
__device__ __forceinline__ u16 f2b(float f) {
    union { float f; unsigned int i; } v; v.f = f;
    unsigned int r = v.i + 0x7fffu + ((v.i >> 16) & 1u);
    return (u16)(r >> 16);
}
__device__ __forceinline__ float gelu_f(float x) {
    float z = 0.7978845608028654f * (x + 0.044715f * x * x * x);
    float e = __expf(2.0f * z);
    float t = 1.0f - 2.0f / (e + 1.0f);   // tanh(z), safe at e=inf
    return 0.5f * x * (1.0f + t);
}

// ---- dtype detector: bf16-read exponent >= 2^60 anywhere => fp32 input
__global__ __launch_bounds__(256)
void detect_k(const u16* __restrict__ x, int* __restrict__ flag)
{
    int tid = threadIdx.x;
    int bad = 0;
    for (int i = tid; i < 65536; i += 256) {
        int e = (x[i] >> 7) & 0xFF;
        if (e >= 187) bad = 1;               // |v| >= 2^60: impossible for N(0,1) bf16
    }
    unsigned long long m = __ballot(bad != 0);
    __shared__ int sh[4];
    if ((tid & 63) == 0) sh[tid >> 6] = (m != 0ull) ? 1 : 0;
    __syncthreads();
    if (tid == 0) flag[0] = sh[0] | sh[1] | sh[2] | sh[3];
}

// ---- input converter: fp32->bf16 if flag, else u16 copy
__global__ __launch_bounds__(256)
void conv_k(const void* __restrict__ src, u16* __restrict__ dst, long n,
            const int* __restrict__ flag)
{
    long i = (long)blockIdx.x * 256 + threadIdx.x;
    long stride = (long)gridDim.x * 256;
    if (*flag) {
        const float* s = (const float*)src;
        for (; i < n; i += stride) dst[i] = f2b(s[i]);
    } else {
        const u16* s = (const u16*)src;
        for (; i < n; i += stride) dst[i] = s[i];
    }
}

// ---------------- LayerNorm: one block per row of 1024 ----------------
__global__ __launch_bounds__(256)
void ln_k(const u16* __restrict__ x, const u16* __restrict__ g,
          const u16* __restrict__ b, u16* __restrict__ o)
{
    long row = blockIdx.x;
    int tid = threadIdx.x;
    const u16x4 u = *(const u16x4*)(x + row * 1024 + tid * 4);
    float v0 = b2f(u[0]), v1 = b2f(u[1]), v2 = b2f(u[2]), v3 = b2f(u[3]);
    float s  = v0 + v1 + v2 + v3;
    float sq = v0*v0 + v1*v1 + v2*v2 + v3*v3;
    #pragma unroll
    for (int off = 32; off; off >>= 1) { s += __shfl_xor(s, off); sq += __shfl_xor(sq, off); }
    __shared__ float sm[8];
    int wid = tid >> 6, lane = tid & 63;
    if (lane == 0) { sm[wid] = s; sm[wid + 4] = sq; }
    __syncthreads();
    s  = sm[0] + sm[1] + sm[2] + sm[3];
    sq = sm[4] + sm[5] + sm[6] + sm[7];
    float mean = s * (1.0f / 1024.0f);
    float var  = sq * (1.0f / 1024.0f) - mean * mean;
    float rs   = rsqrtf(var + 1e-5f);
    u16x4 gg = *(const u16x4*)(g + tid * 4);
    u16x4 bb = *(const u16x4*)(b + tid * 4);
    u16x4 ov;
    ov[0] = f2b((v0 - mean) * rs * b2f(gg[0]) + b2f(bb[0]));
    ov[1] = f2b((v1 - mean) * rs * b2f(gg[1]) + b2f(bb[1]));
    ov[2] = f2b((v2 - mean) * rs * b2f(gg[2]) + b2f(bb[2]));
    ov[3] = f2b((v3 - mean) * rs * b2f(gg[3]) + b2f(bb[3]));
    *(u16x4*)(o + row * 1024 + tid * 4) = ov;
}

// -------- Softmax (causal, in-place), one wave per row; per-batch base
__global__ __launch_bounds__(256)
void softmax_k(u16* __restrict__ probs)
{
    int wid = threadIdx.x >> 6, lane = threadIdx.x & 63;
    long rid = (long)blockIdx.x * 4 + wid;          // 16384 rows = H*S
    int q = (int)(rid & 1023);
    u16* row = probs + rid * 1024;
    float v[16];
    float m = -3.0e38f;
    #pragma unroll
    for (int c = 0; c < 2; c++) {
        int kb = (c * 64 + lane) * 8;
        u16x8 u = *(const u16x8*)(row + kb);
        #pragma unroll
        for (int e = 0; e < 8; e++) {
            if (kb + e <= q) {
                float f = b2f(u[e]);
                v[c * 8 + e] = f;
                m = fmaxf(m, f);
            } else {
                v[c * 8 + e] = -3.0e38f;
            }
        }
    }
    #pragma unroll
    for (int off = 32; off; off >>= 1) m = fmaxf(m, __shfl_xor(m, off));
    float s = 0.0f;
    #pragma unroll
    for (int t = 0; t < 16; t++) {
        float e = (v[t] > -1.0e38f) ? __expf(v[t] - m) : 0.0f;
        v[t] = e; s += e;
    }
    #pragma unroll
    for (int off = 32; off; off >>= 1) s += __shfl_xor(s, off);
    float inv = 1.0f / s;
    #pragma unroll
    for (int c = 0; c < 2; c++) {
        int kb = (c * 64 + lane) * 8;
        u16x8 o;
        #pragma unroll
        for (int e = 0; e < 8; e++) o[e] = f2b(v[c * 8 + e] * inv);
        *(u16x8*)(row + kb) = o;
    }
}

// -------- mean over heads -> att_weights; flag-adaptive output store
__global__ __launch_bounds__(256)
void mean_k(const u16* __restrict__ probs, void* __restrict__ ow, long ofs,
            const int* __restrict__ flag)
{
    long vid = (long)blockIdx.x * 256 + threadIdx.x;   // vec8 id, 131072 total
    long base = vid * 8;                               // [0, 1Mi)
    int qq = (int)(base >> 10), k0 = (int)(base & 1023);
    float s[8] = {0,0,0,0,0,0,0,0};
    for (int h = 0; h < 16; h++) {
        const u16x8 u = *(const u16x8*)(probs + (((long)h << 20) + (long)qq * 1024 + k0));
        #pragma unroll
        for (int e = 0; e < 8; e++) s[e] += b2f(u[e]);
    }
    if (*flag) {
        float* o = (float*)ow + ofs + base;
        #pragma unroll
        for (int e = 0; e < 8; e++) o[e] = s[e] * 0.0625f;
    } else {
        u16x8 o;
        #pragma unroll
        for (int e = 0; e < 8; e++) o[e] = f2b(s[e] * 0.0625f);
        *(u16x8*)((u16*)ow + ofs + base) = o;
    }
}

// ---------------- gemm_bt: C[m,n] = sum_k A[m,k]*Bt[n,k] + epilogue ---
// EPI: 1 qkv-routing (+bias), 2 +bias+residual (bf16 store),
//      3 gelu(+bias), 4 scores (scale+causal, tn<=tm only),
//      5 PV (k-limit, bz=head), 6 +bias+residual, flag-adaptive out store
template<int BN, int EPI>
__global__ __launch_bounds__(256)
void gemm_bt(const u16* __restrict__ A, const u16* __restrict__ Bt,
             u16* __restrict__ C, const u16* __restrict__ bias,
             const u16* __restrict__ res,
             u16* __restrict__ qb, u16* __restrict__ kb, u16* __restrict__ vb,
             int M, int N, int K, int lda, int ldb, int ldc,
             long sA, long sB, long sC,
             const int* __restrict__ oflag, void* __restrict__ oout)
{
    constexpr int BM = 128, BK = 32;
    constexpr int WROWS = (BN == 128) ? 2 : 4;
    constexpr int WCOLS = (BN == 128) ? 2 : 1;
    constexpr int WM = BM / WROWS, WN = BN / WCOLS;
    constexpr int MI = WM / 16, NJ = WN / 16;
    constexpr int ACH = BM * BK / 8 / 256;   // A 16B-chunks per thread
    constexpr int BCH = BN * BK / 8 / 256;   // B 16B-chunks per thread

    __shared__ alignas(16) u16 Ash[BM * BK];
    __shared__ alignas(16) u16 Bsh[BN * BK];

    const int tid = threadIdx.x;
    const int tn = blockIdx.x, tm = blockIdx.y, bz = blockIdx.z;
    if (EPI == 4 && tn > tm) return;   // fully-masked causal tile

    const u16* Ab = A + (long)bz * sA;
    const u16* Bb = Bt + (long)bz * sB;

    const int m0 = tm * BM, n0 = tn * BN;
    const int kEff = (EPI == 5) ? (((tm + 1) * BM < K) ? (tm + 1) * BM : K) : K;

    const int w = tid >> 6, lane = tid & 63;
    const int wrow = w % WROWS, wcol = w / WROWS;
    const int mw = wrow * WM, nw = wcol * WN;
    const int lr = lane & 15, quad = lane >> 4;

    f32x4 acc[MI][NJ] = {};

    for (int k0 = 0; k0 < kEff; k0 += BK) {
        u16x8 atmp[ACH], btmp[BCH];
        #pragma unroll
        for (int i = 0; i < ACH; i++) {
            int c = i * 256 + tid;
            int row = c >> 2, col = (c & 3) * 8;
            atmp[i] = *(const u16x8*)(Ab + (long)(m0 + row) * lda + k0 + col);
        }
        #pragma unroll
        for (int i = 0; i < BCH; i++) {
            int c = i * 256 + tid;
            int row = c >> 2, col = (c & 3) * 8;
            btmp[i] = *(const u16x8*)(Bb + (long)(n0 + row) * ldb + k0 + col);
        }
        __syncthreads();   // previous tile's LDS readers done
        #pragma unroll
        for (int i = 0; i < ACH; i++) { int c = i * 256 + tid; *(u16x8*)&Ash[c * 8] = atmp[i]; }
        #pragma unroll
        for (int i = 0; i < BCH; i++) { int c = i * 256 + tid; *(u16x8*)&Bsh[c * 8] = btmp[i]; }
        __syncthreads();

        s16x8 af[MI], bfr[NJ];
        #pragma unroll
        for (int i = 0; i < MI; i++)
            af[i] = *(const s16x8*)&Ash[(mw + i * 16 + lr) * BK + quad * 8];
        #pragma unroll
        for (int j = 0; j < NJ; j++)
            bfr[j] = *(const s16x8*)&Bsh[(nw + j * 16 + lr) * BK + quad * 8];
        #pragma unroll
        for (int i = 0; i < MI; i++)
            #pragma unroll
            for (int j = 0; j < NJ; j++)
                acc[i][j] = __builtin_amdgcn_mfma_f32_16x16x32_bf16(af[i], bfr[j], acc[i][j], 0, 0, 0);
    }

    u16* Cb;
    if (EPI == 5) Cb = C + (long)bz * 64;    // bz = head, C = att + b*2^20
    else          Cb = C + (long)bz * sC;

    #pragma unroll
    for (int i = 0; i < MI; i++) {
        #pragma unroll
        for (int j = 0; j < NJ; j++) {
            #pragma unroll
            for (int r = 0; r < 4; r++) {
                int gm = m0 + mw + i * 16 + quad * 4 + r;
                int gn = n0 + nw + j * 16 + lr;
                float v = acc[i][j][r];
                if (EPI == 5) {
                    Cb[(long)gm * ldc + gn] = f2b(v);
                } else if (EPI == 1) {
                    v += b2f(bias[gn]);
                    int b = gm >> 10, s = gm & 1023;
                    int sel = gn >> 10, nn = gn & 1023, hh = nn >> 6, d = nn & 63;
                    long bh = b * 16 + hh;
                    if (sel == 0)      qb[(bh * 1024 + s) * 64 + d] = f2b(v);
                    else if (sel == 1) kb[(bh * 1024 + s) * 64 + d] = f2b(v);
                    else               vb[(bh * 64 + d) * 1024 + s] = f2b(v);
                } else if (EPI == 2) {
                    v += b2f(bias[gn]) + b2f(res[(long)gm * ldc + gn]);
                    Cb[(long)gm * ldc + gn] = f2b(v);
                } else if (EPI == 3) {
                    Cb[(long)gm * ldc + gn] = f2b(gelu_f(v + b2f(bias[gn])));
                } else if (EPI == 4) {
                    if (gn <= gm) Cb[(long)gm * ldc + gn] = f2b(v * 0.125f);
                } else if (EPI == 6) {
                    v += b2f(bias[gn]) + b2f(res[(long)gm * ldc + gn]);
                    long idx = (long)gm * ldc + gn;
                    if (*oflag) ((float*)oout)[idx] = v;
                    else        ((u16*)oout)[idx]   = f2b(v);
                }
            }
        }
    }
}

extern "C" void kernel_launch(void* const* d_in, const int* in_sizes, int n_in,
                              void* d_out, int out_size, void* d_ws, size_t ws_size,
                              hipStream_t stream)
{
    const long MEG = 1L << 20;
    const long KI  = 1024;

    u16* ws = (u16*)d_ws;
    // converted-input region
    u16* xc    = ws;                    // 4Mi (becomes x2 in-place at GEMM2)
    u16* winC  = ws + 4  * MEG;         // 3Mi
    u16* woutC = ws + 7  * MEG;         // 1Mi
    u16* wfcC  = ws + 8  * MEG;         // 4Mi
    u16* wprjC = ws + 12 * MEG;         // 4Mi
    u16* sm    = ws + 16 * MEG;         // small params, 4Ki-slotted
    u16* ln1g = sm + 0*4*KI, *ln1b = sm + 1*4*KI;
    u16* ln2g = sm + 2*4*KI, *ln2b = sm + 3*4*KI;
    u16* binC = sm + 4*4*KI;            // 3Ki
    u16* boutC= sm + 5*4*KI;
    u16* bfcC = sm + 6*4*KI;            // 4Ki
    u16* bprjC= sm + 7*4*KI;
    int* flag = (int*)(sm + 8*4*KI);
    u16* slotA = ws + 16 * MEG + 64 * KI;   // 4Mi: h / att / h2
    u16* qB    = slotA + 4  * MEG;      // (B,H,S,DH)
    u16* kB    = slotA + 8  * MEG;      // (B,H,S,DH)
    u16* vT    = slotA + 12 * MEG;      // (B,H,DH,S)
    u16* probs = slotA + 16 * MEG;      // per-batch (H,S,S) 16Mi; reused as act

    // 0. detect input dtype (fp32 vs bf16), convert all float inputs to bf16
    detect_k<<<1, 256, 0, stream>>>((const u16*)d_in[0], flag);
    conv_k<<<2048, 256, 0, stream>>>(d_in[0],  xc,    4*MEG, flag);
    conv_k<<<2048, 256, 0, stream>>>(d_in[6],  winC,  3*MEG, flag);
    conv_k<<<1024, 256, 0, stream>>>(d_in[8],  woutC, 1*MEG, flag);
    conv_k<<<2048, 256, 0, stream>>>(d_in[10], wfcC,  4*MEG, flag);
    conv_k<<<2048, 256, 0, stream>>>(d_in[12], wprjC, 4*MEG, flag);
    conv_k<<<4, 256, 0, stream>>>(d_in[2],  ln1g, 1024, flag);
    conv_k<<<4, 256, 0, stream>>>(d_in[3],  ln1b, 1024, flag);
    conv_k<<<4, 256, 0, stream>>>(d_in[4],  ln2g, 1024, flag);
    conv_k<<<4, 256, 0, stream>>>(d_in[5],  ln2b, 1024, flag);
    conv_k<<<12, 256, 0, stream>>>(d_in[7],  binC, 3072, flag);
    conv_k<<<4, 256, 0, stream>>>(d_in[9],  boutC, 1024, flag);
    conv_k<<<16, 256, 0, stream>>>(d_in[11], bfcC, 4096, flag);
    conv_k<<<4, 256, 0, stream>>>(d_in[13], bprjC, 1024, flag);

    u16* h   = slotA;   // LN1 out
    u16* att = slotA;   // attention out (h dead after QKV)
    u16* h2  = slotA;   // LN2 out (att dead after GEMM2)
    u16* act = probs;

    // 1. LN1
    ln_k<<<4096, 256, 0, stream>>>(xc, ln1g, ln1b, h);
    // 2. QKV projection, routed to q/k/v^T layouts
    gemm_bt<128, 1><<<dim3(24, 32, 1), 256, 0, stream>>>(
        h, winC, nullptr, binC, nullptr, qB, kB, vT,
        4096, 3072, 1024, 1024, 1024, 0, 0, 0, 0, nullptr, nullptr);
    // 3-6. attention, one batch at a time (probs buffer reused)
    for (int b = 0; b < 4; b++) {
        const u16* qb_ = qB + b * MEG;
        const u16* kb_ = kB + b * MEG;
        const u16* vt_ = vT + b * MEG;
        u16* att_ = att + b * MEG;
        gemm_bt<128, 4><<<dim3(8, 8, 16), 256, 0, stream>>>(
            qb_, kb_, probs, nullptr, nullptr, nullptr, nullptr, nullptr,
            1024, 1024, 64, 64, 64, 1024, 65536, 65536, 1048576, nullptr, nullptr);
        softmax_k<<<4096, 256, 0, stream>>>(probs);
        gemm_bt<64, 5><<<dim3(1, 8, 16), 256, 0, stream>>>(
            probs, vt_, att_, nullptr, nullptr, nullptr, nullptr, nullptr,
            1024, 64, 1024, 1024, 1024, 1024, 1048576, 65536, 0, nullptr, nullptr);
        // att_weights = mean over heads -> output 1 (flag-adaptive store)
        mean_k<<<512, 256, 0, stream>>>(probs, d_out, 4 * MEG + b * MEG, flag);
    }
    // 7. x2 = x + att @ w_out^T + b_out   (in-place over xc: 1 writer/elem)
    gemm_bt<128, 2><<<dim3(8, 32, 1), 256, 0, stream>>>(
        att, woutC, xc, boutC, xc, nullptr, nullptr, nullptr,
        4096, 1024, 1024, 1024, 1024, 1024, 0, 0, 0, nullptr, nullptr);
    // 8. LN2
    ln_k<<<4096, 256, 0, stream>>>(xc, ln2g, ln2b, h2);
    // 9. act = gelu(h2 @ w_fc^T + b_fc)
    gemm_bt<128, 3><<<dim3(32, 32, 1), 256, 0, stream>>>(
        h2, wfcC, act, bfcC, nullptr, nullptr, nullptr, nullptr,
        4096, 4096, 1024, 1024, 1024, 4096, 0, 0, 0, nullptr, nullptr);
    // 10. out = x2 + act @ w_proj^T + b_proj  -> output 0 (flag-adaptive)
    gemm_bt<128, 6><<<dim3(8, 32, 1), 256, 0, stream>>>(
        act, wprjC, nullptr, bprjC, xc, nullptr, nullptr, nullptr,
        4096, 1024, 4096, 4096, 4096, 1024, 0, 0, 0, flag, d_out);
}

// Round 4
// 575.164 us; speedup vs baseline: 1.2045x; 1.2045x over previous
//
#include <hip/hip_runtime.h>

typedef unsigned short u16;
typedef u16   u16x4 __attribute__((ext_vector_type(4)));
typedef u16   u16x8 __attribute__((ext_vector_type(8)));
typedef short s16x8 __attribute__((ext_vector_type(8)));
typedef float f32x4 __attribute__((ext_vector_type(4)));

__device__ __forceinline__ float b2f(u16 u) {
    union { unsigned int i; float f; } v; v.i = ((unsigned int)u) << 16; return v.f;
}
__device__ __forceinline__ u16 f2b(float f) {
    union { float f; unsigned int i; } v; v.f = f;
    unsigned int r = v.i + 0x7fffu + ((v.i >> 16) & 1u);
    return (u16)(r >> 16);
}
__device__ __forceinline__ float gelu_f(float x) {
    float z = 0.7978845608028654f * (x + 0.044715f * x * x * x);
    float e = __expf(2.0f * z);
    float t = 1.0f - 2.0f / (e + 1.0f);   // tanh(z), safe at e=inf
    return 0.5f * x * (1.0f + t);
}
__device__ __forceinline__ void async16(const u16* g, u16* l) {
    __builtin_amdgcn_global_load_lds(
        (const __attribute__((address_space(1))) unsigned int*)g,
        (__attribute__((address_space(3))) unsigned int*)l,
        16, 0, 0);
}

// ---- dtype detector: bf16-read exponent >= 2^60 anywhere => fp32 input
__global__ __launch_bounds__(256)
void detect_k(const u16* __restrict__ x, int* __restrict__ flag)
{
    int tid = threadIdx.x;
    int bad = 0;
    for (int i = tid; i < 65536; i += 256) {
        int e = (x[i] >> 7) & 0xFF;
        if (e >= 187) bad = 1;               // |v| >= 2^60: impossible for N(0,1) bf16
    }
    unsigned long long m = __ballot(bad != 0);
    __shared__ int sh[4];
    if ((tid & 63) == 0) sh[tid >> 6] = (m != 0ull) ? 1 : 0;
    __syncthreads();
    if (tid == 0) flag[0] = sh[0] | sh[1] | sh[2] | sh[3];
}

// ---- fused big-tensor converter: x|w_in|w_out|w_fc|w_proj -> ws[0..16Mi)
__global__ __launch_bounds__(256)
void conv_big_k(const void* __restrict__ s0, const void* __restrict__ s1,
                const void* __restrict__ s2, const void* __restrict__ s3,
                const void* __restrict__ s4, u16* __restrict__ dst,
                const int* __restrict__ flag)
{
    const long MEG = 1L << 20;
    long gid = (long)blockIdx.x * 256 + threadIdx.x;   // < 16Mi
    const void* s; long off;
    if      (gid <  4*MEG) { s = s0; off = gid; }
    else if (gid <  7*MEG) { s = s1; off = gid - 4*MEG; }
    else if (gid <  8*MEG) { s = s2; off = gid - 7*MEG; }
    else if (gid < 12*MEG) { s = s3; off = gid - 8*MEG; }
    else                   { s = s4; off = gid - 12*MEG; }
    dst[gid] = (*flag) ? f2b(((const float*)s)[off]) : ((const u16*)s)[off];
}

// ---- fused small-param converter into 4Ki-slotted region
__global__ __launch_bounds__(256)
void conv_small_k(const void* s0, const void* s1, const void* s2, const void* s3,
                  const void* s4, const void* s5, const void* s6, const void* s7,
                  u16* __restrict__ dst, const int* __restrict__ flag)
{
    int gid = blockIdx.x * 256 + threadIdx.x;          // < 13312
    int seg, off;
    if      (gid <  4096) { seg = gid >> 10;  off = gid & 1023; }
    else if (gid <  7168) { seg = 4; off = gid - 4096; }
    else if (gid <  8192) { seg = 5; off = gid - 7168; }
    else if (gid < 12288) { seg = 6; off = gid - 8192; }
    else                  { seg = 7; off = gid - 12288; }
    const void* srcs[8] = {s0, s1, s2, s3, s4, s5, s6, s7};
    const void* s = srcs[seg];
    dst[seg * 4096 + off] = (*flag) ? f2b(((const float*)s)[off]) : ((const u16*)s)[off];
}

// ---------------- LayerNorm: one block per row of 1024 ----------------
__global__ __launch_bounds__(256)
void ln_k(const u16* __restrict__ x, const u16* __restrict__ g,
          const u16* __restrict__ b, u16* __restrict__ o)
{
    long row = blockIdx.x;
    int tid = threadIdx.x;
    const u16x4 u = *(const u16x4*)(x + row * 1024 + tid * 4);
    float v0 = b2f(u[0]), v1 = b2f(u[1]), v2 = b2f(u[2]), v3 = b2f(u[3]);
    float s  = v0 + v1 + v2 + v3;
    float sq = v0*v0 + v1*v1 + v2*v2 + v3*v3;
    #pragma unroll
    for (int off = 32; off; off >>= 1) { s += __shfl_xor(s, off); sq += __shfl_xor(sq, off); }
    __shared__ float sm[8];
    int wid = tid >> 6, lane = tid & 63;
    if (lane == 0) { sm[wid] = s; sm[wid + 4] = sq; }
    __syncthreads();
    s  = sm[0] + sm[1] + sm[2] + sm[3];
    sq = sm[4] + sm[5] + sm[6] + sm[7];
    float mean = s * (1.0f / 1024.0f);
    float var  = sq * (1.0f / 1024.0f) - mean * mean;
    float rs   = rsqrtf(var + 1e-5f);
    u16x4 gg = *(const u16x4*)(g + tid * 4);
    u16x4 bb = *(const u16x4*)(b + tid * 4);
    u16x4 ov;
    ov[0] = f2b((v0 - mean) * rs * b2f(gg[0]) + b2f(bb[0]));
    ov[1] = f2b((v1 - mean) * rs * b2f(gg[1]) + b2f(bb[1]));
    ov[2] = f2b((v2 - mean) * rs * b2f(gg[2]) + b2f(bb[2]));
    ov[3] = f2b((v3 - mean) * rs * b2f(gg[3]) + b2f(bb[3]));
    *(u16x4*)(o + row * 1024 + tid * 4) = ov;
}

// -------- Softmax (causal, in-place), one wave per row --------
__global__ __launch_bounds__(256)
void softmax_k(u16* __restrict__ probs)
{
    int wid = threadIdx.x >> 6, lane = threadIdx.x & 63;
    long rid = (long)blockIdx.x * 4 + wid;          // chunk*16384 rows
    int q = (int)(rid & 1023);
    u16* row = probs + rid * 1024;
    float v[16];
    float m = -3.0e38f;
    #pragma unroll
    for (int c = 0; c < 2; c++) {
        int kb = (c * 64 + lane) * 8;
        if (kb <= q) {                              // skip loads above diagonal
            u16x8 u = *(const u16x8*)(row + kb);
            #pragma unroll
            for (int e = 0; e < 8; e++) {
                if (kb + e <= q) {
                    float f = b2f(u[e]);
                    v[c * 8 + e] = f;
                    m = fmaxf(m, f);
                } else v[c * 8 + e] = -3.0e38f;
            }
        } else {
            #pragma unroll
            for (int e = 0; e < 8; e++) v[c * 8 + e] = -3.0e38f;
        }
    }
    #pragma unroll
    for (int off = 32; off; off >>= 1) m = fmaxf(m, __shfl_xor(m, off));
    float s = 0.0f;
    #pragma unroll
    for (int t = 0; t < 16; t++) {
        float e = (v[t] > -1.0e38f) ? __expf(v[t] - m) : 0.0f;
        v[t] = e; s += e;
    }
    #pragma unroll
    for (int off = 32; off; off >>= 1) s += __shfl_xor(s, off);
    float inv = 1.0f / s;
    #pragma unroll
    for (int c = 0; c < 2; c++) {
        int kb = (c * 64 + lane) * 8;
        u16x8 o;
        #pragma unroll
        for (int e = 0; e < 8; e++) o[e] = f2b(v[c * 8 + e] * inv);
        *(u16x8*)(row + kb) = o;
    }
}

// -------- mean over heads -> att_weights; chunk-aware, skips upper tri
__global__ __launch_bounds__(256)
void mean_k(const u16* __restrict__ probs, void* __restrict__ ow, long ofs,
            const int* __restrict__ flag)
{
    const long MEG = 1L << 20;
    long vid = (long)blockIdx.x * 256 + threadIdx.x;   // chunk*131072 vec8 ids
    int  bl  = (int)(vid >> 17);                       // batch within chunk
    long r   = vid & 131071;
    long base = r * 8;
    int qq = (int)(base >> 10), k0 = (int)(base & 1023);
    float s[8] = {0,0,0,0,0,0,0,0};
    if (k0 <= qq) {                                    // below/at diagonal only
        const u16* pb = probs + ((long)bl << 24);
        for (int h = 0; h < 16; h++) {
            const u16x8 u = *(const u16x8*)(pb + (((long)h << 20) + (long)qq * 1024 + k0));
            #pragma unroll
            for (int e = 0; e < 8; e++) s[e] += b2f(u[e]);
        }
    }
    long idx = ofs + (long)bl * MEG + base;
    if (*flag) {
        float* o = (float*)ow + idx;
        #pragma unroll
        for (int e = 0; e < 8; e++) o[e] = s[e] * 0.0625f;
    } else {
        u16x8 o;
        #pragma unroll
        for (int e = 0; e < 8; e++) o[e] = f2b(s[e] * 0.0625f);
        *(u16x8*)((u16*)ow + idx) = o;
    }
}

// ---------------- gemm_bt: C[m,n] = sum_k A[m,k]*Bt[n,k] + epilogue ---
// EPI: 1 qkv-routing (+bias), 2 +bias+residual (bf16 store),
//      3 gelu(+bias), 4 scores (scale+causal, tn<=tm only),
//      5 PV (k-limit, bz=b*16+h), 6 +bias+residual, flag-adaptive out store
template<int BN, int EPI>
__global__ __launch_bounds__(256)
void gemm_bt(const u16* __restrict__ A, const u16* __restrict__ Bt,
             u16* __restrict__ C, const u16* __restrict__ bias,
             const u16* __restrict__ res,
             u16* __restrict__ qb, u16* __restrict__ kb, u16* __restrict__ vb,
             int M, int N, int K, int lda, int ldb, int ldc,
             long sA, long sB, long sC,
             const int* __restrict__ oflag, void* __restrict__ oout)
{
    constexpr int BM = 128, BK = 32;
    constexpr int WROWS = (BN == 128) ? 2 : 4;
    constexpr int WCOLS = (BN == 128) ? 2 : 1;
    constexpr int WM = BM / WROWS, WN = BN / WCOLS;
    constexpr int MI = WM / 16, NJ = WN / 16;
    constexpr int ACH = BM * BK / 8 / 256;   // A 16B-chunks per thread
    constexpr int BCH = BN * BK / 8 / 256;   // B 16B-chunks per thread

    __shared__ alignas(16) u16 Ash[BM * BK];
    __shared__ alignas(16) u16 Bsh[BN * BK];

    const int tid = threadIdx.x;
    const int tn = blockIdx.x, tm = blockIdx.y, bz = blockIdx.z;
    if (EPI == 4 && tn > tm) return;   // fully-masked causal tile

    const u16* Ab = A + (long)bz * sA;
    const u16* Bb = Bt + (long)bz * sB;

    const int m0 = tm * BM, n0 = tn * BN;
    const int kEff = (EPI == 5) ? (((tm + 1) * BM < K) ? (tm + 1) * BM : K) : K;

    const int w = tid >> 6, lane = tid & 63;
    const int wrow = w % WROWS, wcol = w / WROWS;
    const int mw = wrow * WM, nw = wcol * WN;
    const int lr = lane & 15, quad = lane >> 4;

    f32x4 acc[MI][NJ] = {};

    for (int k0 = 0; k0 < kEff; k0 += BK) {
        __syncthreads();   // previous tile's LDS readers done
        #pragma unroll
        for (int i = 0; i < ACH; i++) {
            int c = i * 256 + tid;
            int row = c >> 2, col = (c & 3) * 8;
            async16(Ab + (long)(m0 + row) * lda + k0 + col, &Ash[c * 8]);
        }
        #pragma unroll
        for (int i = 0; i < BCH; i++) {
            int c = i * 256 + tid;
            int row = c >> 2, col = (c & 3) * 8;
            async16(Bb + (long)(n0 + row) * ldb + k0 + col, &Bsh[c * 8]);
        }
        __syncthreads();   // drains vmcnt (async LDS writes landed)

        s16x8 af[MI], bfr[NJ];
        #pragma unroll
        for (int i = 0; i < MI; i++)
            af[i] = *(const s16x8*)&Ash[(mw + i * 16 + lr) * BK + quad * 8];
        #pragma unroll
        for (int j = 0; j < NJ; j++)
            bfr[j] = *(const s16x8*)&Bsh[(nw + j * 16 + lr) * BK + quad * 8];
        #pragma unroll
        for (int i = 0; i < MI; i++)
            #pragma unroll
            for (int j = 0; j < NJ; j++)
                acc[i][j] = __builtin_amdgcn_mfma_f32_16x16x32_bf16(af[i], bfr[j], acc[i][j], 0, 0, 0);
    }

    u16* Cb;
    if (EPI == 5) Cb = C + (long)(bz >> 4) * (1 << 20) + (bz & 15) * 64;
    else          Cb = C + (long)bz * sC;

    #pragma unroll
    for (int i = 0; i < MI; i++) {
        #pragma unroll
        for (int j = 0; j < NJ; j++) {
            #pragma unroll
            for (int r = 0; r < 4; r++) {
                int gm = m0 + mw + i * 16 + quad * 4 + r;
                int gn = n0 + nw + j * 16 + lr;
                float v = acc[i][j][r];
                if (EPI == 5) {
                    Cb[(long)gm * ldc + gn] = f2b(v);
                } else if (EPI == 1) {
                    v += b2f(bias[gn]);
                    int b = gm >> 10, s = gm & 1023;
                    int sel = gn >> 10, nn = gn & 1023, hh = nn >> 6, d = nn & 63;
                    long bh = b * 16 + hh;
                    if (sel == 0)      qb[(bh * 1024 + s) * 64 + d] = f2b(v);
                    else if (sel == 1) kb[(bh * 1024 + s) * 64 + d] = f2b(v);
                    else               vb[(bh * 64 + d) * 1024 + s] = f2b(v);
                } else if (EPI == 2) {
                    v += b2f(bias[gn]) + b2f(res[(long)gm * ldc + gn]);
                    Cb[(long)gm * ldc + gn] = f2b(v);
                } else if (EPI == 3) {
                    Cb[(long)gm * ldc + gn] = f2b(gelu_f(v + b2f(bias[gn])));
                } else if (EPI == 4) {
                    if (gn <= gm) Cb[(long)gm * ldc + gn] = f2b(v * 0.125f);
                } else if (EPI == 6) {
                    v += b2f(bias[gn]) + b2f(res[(long)gm * ldc + gn]);
                    long idx = (long)gm * ldc + gn;
                    if (*oflag) ((float*)oout)[idx] = v;
                    else        ((u16*)oout)[idx]   = f2b(v);
                }
            }
        }
    }
}

extern "C" void kernel_launch(void* const* d_in, const int* in_sizes, int n_in,
                              void* d_out, int out_size, void* d_ws, size_t ws_size,
                              hipStream_t stream)
{
    const long MEG = 1L << 20;
    const long KI  = 1024;

    u16* ws = (u16*)d_ws;
    // converted-input region (contiguous, order matches conv_big_k)
    u16* xc    = ws;                    // 4Mi (becomes x2 in-place at GEMM2)
    u16* winC  = ws + 4  * MEG;         // 3Mi
    u16* woutC = ws + 7  * MEG;         // 1Mi
    u16* wfcC  = ws + 8  * MEG;         // 4Mi
    u16* wprjC = ws + 12 * MEG;         // 4Mi
    u16* sm    = ws + 16 * MEG;         // small params, 4Ki-slotted
    u16* ln1g = sm + 0*4*KI, *ln1b = sm + 1*4*KI;
    u16* ln2g = sm + 2*4*KI, *ln2b = sm + 3*4*KI;
    u16* binC = sm + 4*4*KI;
    u16* boutC= sm + 5*4*KI;
    u16* bfcC = sm + 6*4*KI;
    u16* bprjC= sm + 7*4*KI;
    int* flag = (int*)(sm + 8*4*KI);
    u16* slotA = ws + 16 * MEG + 64 * KI;   // 4Mi: h / att / h2
    u16* qB    = slotA + 4  * MEG;      // (B,H,S,DH)
    u16* kB    = slotA + 8  * MEG;      // (B,H,S,DH)
    u16* vT    = slotA + 12 * MEG;      // (B,H,DH,S)
    u16* probs = slotA + 16 * MEG;      // chunk*(H,S,S); reused as act (16Mi)

    // attention batch-chunk size from available workspace
    const long fixed_elems = 32 * MEG + 64 * KI;
    const long avail = (long)(ws_size / 2);
    int chunk = 1;
    if      (avail >= fixed_elems + 64 * MEG) chunk = 4;
    else if (avail >= fixed_elems + 32 * MEG) chunk = 2;

    // 0. detect input dtype; convert everything to bf16 in ws
    detect_k<<<1, 256, 0, stream>>>((const u16*)d_in[0], flag);
    conv_big_k<<<65536, 256, 0, stream>>>(d_in[0], d_in[6], d_in[8], d_in[10],
                                          d_in[12], ws, flag);
    conv_small_k<<<52, 256, 0, stream>>>(d_in[2], d_in[3], d_in[4], d_in[5],
                                         d_in[7], d_in[9], d_in[11], d_in[13],
                                         sm, flag);

    u16* h   = slotA;   // LN1 out
    u16* att = slotA;   // attention out (h dead after QKV)
    u16* h2  = slotA;   // LN2 out (att dead after GEMM2)
    u16* act = probs;

    // 1. LN1
    ln_k<<<4096, 256, 0, stream>>>(xc, ln1g, ln1b, h);
    // 2. QKV projection, routed to q/k/v^T layouts
    gemm_bt<128, 1><<<dim3(24, 32, 1), 256, 0, stream>>>(
        h, winC, nullptr, binC, nullptr, qB, kB, vT,
        4096, 3072, 1024, 1024, 1024, 0, 0, 0, 0, nullptr, nullptr);
    // 3-6. attention, `chunk` batches per sweep
    for (int b0 = 0; b0 < 4; b0 += chunk) {
        gemm_bt<128, 4><<<dim3(8, 8, 16 * chunk), 256, 0, stream>>>(
            qB + b0 * MEG, kB + b0 * MEG, probs, nullptr, nullptr,
            nullptr, nullptr, nullptr,
            1024, 1024, 64, 64, 64, 1024, 65536, 65536, 1048576, nullptr, nullptr);
        softmax_k<<<4096 * chunk, 256, 0, stream>>>(probs);
        gemm_bt<64, 5><<<dim3(1, 8, 16 * chunk), 256, 0, stream>>>(
            probs, vT + b0 * MEG, att + b0 * MEG, nullptr, nullptr,
            nullptr, nullptr, nullptr,
            1024, 64, 1024, 1024, 1024, 1024, 1048576, 65536, 0, nullptr, nullptr);
        mean_k<<<512 * chunk, 256, 0, stream>>>(probs, d_out, 4 * MEG + b0 * MEG, flag);
    }
    // 7. x2 = x + att @ w_out^T + b_out   (in-place over xc: 1 writer/elem)
    gemm_bt<64, 2><<<dim3(16, 32, 1), 256, 0, stream>>>(
        att, woutC, xc, boutC, xc, nullptr, nullptr, nullptr,
        4096, 1024, 1024, 1024, 1024, 1024, 0, 0, 0, nullptr, nullptr);
    // 8. LN2
    ln_k<<<4096, 256, 0, stream>>>(xc, ln2g, ln2b, h2);
    // 9. act = gelu(h2 @ w_fc^T + b_fc)
    gemm_bt<128, 3><<<dim3(32, 32, 1), 256, 0, stream>>>(
        h2, wfcC, act, bfcC, nullptr, nullptr, nullptr, nullptr,
        4096, 4096, 1024, 1024, 1024, 4096, 0, 0, 0, nullptr, nullptr);
    // 10. out = x2 + act @ w_proj^T + b_proj  -> output 0 (flag-adaptive)
    gemm_bt<64, 6><<<dim3(16, 32, 1), 256, 0, stream>>>(
        act, wprjC, nullptr, bprjC, xc, nullptr, nullptr, nullptr,
        4096, 1024, 4096, 4096, 4096, 1024, 0, 0, 0, flag, d_out);
}

// Round 5
// 536.088 us; speedup vs baseline: 1.2923x; 1.0729x over previous
//
#include <hip/hip_runtime.h>

typedef unsigned short u16;
typedef u16   u16x4 __attribute__((ext_vector_type(4)));
typedef u16   u16x8 __attribute__((ext_vector_type(8)));
typedef short s16x8 __attribute__((ext_vector_type(8)));
typedef float f32x4 __attribute__((ext_vector_type(4)));

__device__ __forceinline__ float b2f(u16 u) {
    union { unsigned int i; float f; } v; v.i = ((unsigned int)u) << 16; return v.f;
}
__device__ __forceinline__ u16 f2b(float f) {
    union { float f; unsigned int i; } v; v.f = f;
    unsigned int r = v.i + 0x7fffu + ((v.i >> 16) & 1u);
    return (u16)(r >> 16);
}
__device__ __forceinline__ float gelu_f(float x) {
    float z = 0.7978845608028654f * (x + 0.044715f * x * x * x);
    float e = __expf(2.0f * z);
    float t = 1.0f - 2.0f / (e + 1.0f);   // tanh(z), safe at e=inf
    return 0.5f * x * (1.0f + t);
}
__device__ __forceinline__ void async16(const u16* g, u16* l) {
    __builtin_amdgcn_global_load_lds(
        (const __attribute__((address_space(1))) unsigned int*)g,
        (__attribute__((address_space(3))) unsigned int*)l,
        16, 0, 0);
}

// ---- dtype detector: bf16-read exponent >= 2^60 anywhere => fp32 input
__global__ __launch_bounds__(256)
void detect_k(const u16* __restrict__ x, int* __restrict__ flag)
{
    int tid = threadIdx.x;
    int bad = 0;
    for (int i = tid; i < 65536; i += 256) {
        int e = (x[i] >> 7) & 0xFF;
        if (e >= 187) bad = 1;               // |v| >= 2^60: impossible for N(0,1) bf16
    }
    unsigned long long m = __ballot(bad != 0);
    __shared__ int sh[4];
    if ((tid & 63) == 0) sh[tid >> 6] = (m != 0ull) ? 1 : 0;
    __syncthreads();
    if (tid == 0) flag[0] = sh[0] | sh[1] | sh[2] | sh[3];
}

// ---- fused big-tensor converter (vec4): x|w_in|w_out|w_fc|w_proj -> ws[0..16Mi)
__global__ __launch_bounds__(256)
void conv_big_k(const void* __restrict__ s0, const void* __restrict__ s1,
                const void* __restrict__ s2, const void* __restrict__ s3,
                const void* __restrict__ s4, u16* __restrict__ dst,
                const int* __restrict__ flag)
{
    const long MEG = 1L << 20;
    long gid = ((long)blockIdx.x * 256 + threadIdx.x) * 4;   // < 16Mi
    const void* s; long off;
    if      (gid <  4*MEG) { s = s0; off = gid; }
    else if (gid <  7*MEG) { s = s1; off = gid - 4*MEG; }
    else if (gid <  8*MEG) { s = s2; off = gid - 7*MEG; }
    else if (gid < 12*MEG) { s = s3; off = gid - 8*MEG; }
    else                   { s = s4; off = gid - 12*MEG; }
    u16x4 o;
    if (*flag) {
        const float4 f = *(const float4*)((const float*)s + off);
        o[0] = f2b(f.x); o[1] = f2b(f.y); o[2] = f2b(f.z); o[3] = f2b(f.w);
    } else {
        o = *(const u16x4*)((const u16*)s + off);
    }
    *(u16x4*)(dst + gid) = o;
}

// ---- fused small-param converter into 4Ki-slotted region
__global__ __launch_bounds__(256)
void conv_small_k(const void* s0, const void* s1, const void* s2, const void* s3,
                  const void* s4, const void* s5, const void* s6, const void* s7,
                  u16* __restrict__ dst, const int* __restrict__ flag)
{
    int gid = blockIdx.x * 256 + threadIdx.x;          // < 13312
    int seg, off;
    if      (gid <  4096) { seg = gid >> 10;  off = gid & 1023; }
    else if (gid <  7168) { seg = 4; off = gid - 4096; }
    else if (gid <  8192) { seg = 5; off = gid - 7168; }
    else if (gid < 12288) { seg = 6; off = gid - 8192; }
    else                  { seg = 7; off = gid - 12288; }
    const void* srcs[8] = {s0, s1, s2, s3, s4, s5, s6, s7};
    const void* s = srcs[seg];
    dst[seg * 4096 + off] = (*flag) ? f2b(((const float*)s)[off]) : ((const u16*)s)[off];
}

// ---------------- LayerNorm: one block per row of 1024 ----------------
__global__ __launch_bounds__(256)
void ln_k(const u16* __restrict__ x, const u16* __restrict__ g,
          const u16* __restrict__ b, u16* __restrict__ o)
{
    long row = blockIdx.x;
    int tid = threadIdx.x;
    const u16x4 u = *(const u16x4*)(x + row * 1024 + tid * 4);
    float v0 = b2f(u[0]), v1 = b2f(u[1]), v2 = b2f(u[2]), v3 = b2f(u[3]);
    float s  = v0 + v1 + v2 + v3;
    float sq = v0*v0 + v1*v1 + v2*v2 + v3*v3;
    #pragma unroll
    for (int off = 32; off; off >>= 1) { s += __shfl_xor(s, off); sq += __shfl_xor(sq, off); }
    __shared__ float sm[8];
    int wid = tid >> 6, lane = tid & 63;
    if (lane == 0) { sm[wid] = s; sm[wid + 4] = sq; }
    __syncthreads();
    s  = sm[0] + sm[1] + sm[2] + sm[3];
    sq = sm[4] + sm[5] + sm[6] + sm[7];
    float mean = s * (1.0f / 1024.0f);
    float var  = sq * (1.0f / 1024.0f) - mean * mean;
    float rs   = rsqrtf(var + 1e-5f);
    u16x4 gg = *(const u16x4*)(g + tid * 4);
    u16x4 bb = *(const u16x4*)(b + tid * 4);
    u16x4 ov;
    ov[0] = f2b((v0 - mean) * rs * b2f(gg[0]) + b2f(bb[0]));
    ov[1] = f2b((v1 - mean) * rs * b2f(gg[1]) + b2f(bb[1]));
    ov[2] = f2b((v2 - mean) * rs * b2f(gg[2]) + b2f(bb[2]));
    ov[3] = f2b((v3 - mean) * rs * b2f(gg[3]) + b2f(bb[3]));
    *(u16x4*)(o + row * 1024 + tid * 4) = ov;
}

// -------- Softmax (causal, in-place), one wave per row --------
// Stores only within the 128-aligned diagonal tile (PV reads exactly
// [0,(tm+1)*128); mean's vec8 never crosses the tile end).
__global__ __launch_bounds__(256)
void softmax_k(u16* __restrict__ probs)
{
    int wid = threadIdx.x >> 6, lane = threadIdx.x & 63;
    long rid = (long)blockIdx.x * 4 + wid;          // chunk*16384 rows
    int q = (int)(rid & 1023);
    int tile_end = ((q >> 7) + 1) << 7;
    u16* row = probs + rid * 1024;
    float v[16];
    float m = -3.0e38f;
    #pragma unroll
    for (int c = 0; c < 2; c++) {
        int kb = (c * 64 + lane) * 8;
        if (kb <= q) {                              // skip loads above diagonal
            u16x8 u = *(const u16x8*)(row + kb);
            #pragma unroll
            for (int e = 0; e < 8; e++) {
                if (kb + e <= q) {
                    float f = b2f(u[e]);
                    v[c * 8 + e] = f;
                    m = fmaxf(m, f);
                } else v[c * 8 + e] = -3.0e38f;
            }
        } else {
            #pragma unroll
            for (int e = 0; e < 8; e++) v[c * 8 + e] = -3.0e38f;
        }
    }
    #pragma unroll
    for (int off = 32; off; off >>= 1) m = fmaxf(m, __shfl_xor(m, off));
    float s = 0.0f;
    #pragma unroll
    for (int t = 0; t < 16; t++) {
        float e = (v[t] > -1.0e38f) ? __expf(v[t] - m) : 0.0f;
        v[t] = e; s += e;
    }
    #pragma unroll
    for (int off = 32; off; off >>= 1) s += __shfl_xor(s, off);
    float inv = 1.0f / s;
    #pragma unroll
    for (int c = 0; c < 2; c++) {
        int kb = (c * 64 + lane) * 8;
        if (kb < tile_end) {
            u16x8 o;
            #pragma unroll
            for (int e = 0; e < 8; e++) o[e] = f2b(v[c * 8 + e] * inv);
            *(u16x8*)(row + kb) = o;
        }
    }
}

// -------- mean over heads -> att_weights; chunk-aware, skips upper tri
__global__ __launch_bounds__(256)
void mean_k(const u16* __restrict__ probs, void* __restrict__ ow, long ofs,
            const int* __restrict__ flag)
{
    const long MEG = 1L << 20;
    long vid = (long)blockIdx.x * 256 + threadIdx.x;   // chunk*131072 vec8 ids
    int  bl  = (int)(vid >> 17);                       // batch within chunk
    long r   = vid & 131071;
    long base = r * 8;
    int qq = (int)(base >> 10), k0 = (int)(base & 1023);
    float s[8] = {0,0,0,0,0,0,0,0};
    if (k0 <= qq) {                                    // below/at diagonal only
        const u16* pb = probs + ((long)bl << 24);
        for (int h = 0; h < 16; h++) {
            const u16x8 u = *(const u16x8*)(pb + (((long)h << 20) + (long)qq * 1024 + k0));
            #pragma unroll
            for (int e = 0; e < 8; e++) s[e] += b2f(u[e]);
        }
    }
    long idx = ofs + (long)bl * MEG + base;
    if (*flag) {
        float* o = (float*)ow + idx;
        #pragma unroll
        for (int e = 0; e < 8; e++) o[e] = s[e] * 0.0625f;
    } else {
        u16x8 o;
        #pragma unroll
        for (int e = 0; e < 8; e++) o[e] = f2b(s[e] * 0.0625f);
        *(u16x8*)((u16*)ow + idx) = o;
    }
}

// ---------------- gemm_bt: C[m,n] = sum_k A[m,k]*Bt[n,k] + epilogue ---
// Single-barrier double-buffered K-loop: prefetch tile k+1 right after the
// barrier, compute tile k; the prefetch drains only at the NEXT barrier.
// EPI: 1 qkv-routing (+bias), 2 +bias+residual (bf16 store),
//      3 gelu(+bias), 4 scores (scale+causal, tn<=tm only),
//      5 PV (k-limit, bz=b*16+h), 6 +bias+residual, flag-adaptive out store
template<int BN, int EPI>
__global__ __launch_bounds__(256)
void gemm_bt(const u16* __restrict__ A, const u16* __restrict__ Bt,
             u16* __restrict__ C, const u16* __restrict__ bias,
             const u16* __restrict__ res,
             u16* __restrict__ qb, u16* __restrict__ kb, u16* __restrict__ vb,
             int M, int N, int K, int lda, int ldb, int ldc,
             long sA, long sB, long sC,
             const int* __restrict__ oflag, void* __restrict__ oout)
{
    constexpr int BM = 128, BK = 32;
    constexpr int WROWS = (BN == 128) ? 2 : 4;
    constexpr int WCOLS = (BN == 128) ? 2 : 1;
    constexpr int WM = BM / WROWS, WN = BN / WCOLS;
    constexpr int MI = WM / 16, NJ = WN / 16;
    constexpr int ACH = BM * BK / 8 / 256;   // A 16B-chunks per thread
    constexpr int BCH = BN * BK / 8 / 256;   // B 16B-chunks per thread

    __shared__ alignas(16) u16 Ash[2][BM * BK];
    __shared__ alignas(16) u16 Bsh[2][BN * BK];

    const int tid = threadIdx.x;
    const int tn = blockIdx.x, tm = blockIdx.y, bz = blockIdx.z;
    if (EPI == 4 && tn > tm) return;   // fully-masked causal tile

    const u16* Ab = A + (long)bz * sA;
    const u16* Bb = Bt + (long)bz * sB;

    const int m0 = tm * BM, n0 = tn * BN;
    const int kEff = (EPI == 5) ? (((tm + 1) * BM < K) ? (tm + 1) * BM : K) : K;

    const int w = tid >> 6, lane = tid & 63;
    const int wrow = w % WROWS, wcol = w / WROWS;
    const int mw = wrow * WM, nw = wcol * WN;
    const int lr = lane & 15, quad = lane >> 4;

    // staging addresses for this thread (row/col within tile fixed)
    const int ca0 = tid, ca1 = 256 + tid;            // A chunk ids (ACH=2)
    const int ar0 = ca0 >> 2, ac0 = (ca0 & 3) * 8;
    const int ar1 = ca1 >> 2, ac1 = (ca1 & 3) * 8;
    const int cb0 = tid;                              // B chunk id 0
    const int br0 = cb0 >> 2, bc0 = (cb0 & 3) * 8;
    const int cb1 = 256 + tid;                        // only if BCH==2
    const int br1 = cb1 >> 2, bc1 = (cb1 & 3) * 8;

    auto stage = [&](int buf, int k0) {
        async16(Ab + (long)(m0 + ar0) * lda + k0 + ac0, &Ash[buf][ca0 * 8]);
        async16(Ab + (long)(m0 + ar1) * lda + k0 + ac1, &Ash[buf][ca1 * 8]);
        async16(Bb + (long)(n0 + br0) * ldb + k0 + bc0, &Bsh[buf][cb0 * 8]);
        if (BCH == 2)
            async16(Bb + (long)(n0 + br1) * ldb + k0 + bc1, &Bsh[buf][cb1 * 8]);
    };

    f32x4 acc[MI][NJ] = {};

    stage(0, 0);
    int cur = 0;
    for (int k0 = 0; k0 < kEff; k0 += BK) {
        __syncthreads();   // drains cur's loads; fences prior readers of nxt
        if (k0 + BK < kEff) stage(cur ^ 1, k0 + BK);

        s16x8 af[MI], bfr[NJ];
        #pragma unroll
        for (int i = 0; i < MI; i++)
            af[i] = *(const s16x8*)&Ash[cur][(mw + i * 16 + lr) * BK + quad * 8];
        #pragma unroll
        for (int j = 0; j < NJ; j++)
            bfr[j] = *(const s16x8*)&Bsh[cur][(nw + j * 16 + lr) * BK + quad * 8];
        #pragma unroll
        for (int i = 0; i < MI; i++)
            #pragma unroll
            for (int j = 0; j < NJ; j++)
                acc[i][j] = __builtin_amdgcn_mfma_f32_16x16x32_bf16(af[i], bfr[j], acc[i][j], 0, 0, 0);
        cur ^= 1;
    }

    u16* Cb;
    if (EPI == 5) Cb = C + (long)(bz >> 4) * (1 << 20) + (bz & 15) * 64;
    else          Cb = C + (long)bz * sC;

    #pragma unroll
    for (int i = 0; i < MI; i++) {
        #pragma unroll
        for (int j = 0; j < NJ; j++) {
            #pragma unroll
            for (int r = 0; r < 4; r++) {
                int gm = m0 + mw + i * 16 + quad * 4 + r;
                int gn = n0 + nw + j * 16 + lr;
                float v = acc[i][j][r];
                if (EPI == 5) {
                    Cb[(long)gm * ldc + gn] = f2b(v);
                } else if (EPI == 1) {
                    v += b2f(bias[gn]);
                    int b = gm >> 10, s = gm & 1023;
                    int sel = gn >> 10, nn = gn & 1023, hh = nn >> 6, d = nn & 63;
                    long bh = b * 16 + hh;
                    if (sel == 0)      qb[(bh * 1024 + s) * 64 + d] = f2b(v);
                    else if (sel == 1) kb[(bh * 1024 + s) * 64 + d] = f2b(v);
                    else               vb[(bh * 64 + d) * 1024 + s] = f2b(v);
                } else if (EPI == 2) {
                    v += b2f(bias[gn]) + b2f(res[(long)gm * ldc + gn]);
                    Cb[(long)gm * ldc + gn] = f2b(v);
                } else if (EPI == 3) {
                    Cb[(long)gm * ldc + gn] = f2b(gelu_f(v + b2f(bias[gn])));
                } else if (EPI == 4) {
                    if (gn <= gm) Cb[(long)gm * ldc + gn] = f2b(v * 0.125f);
                } else if (EPI == 6) {
                    v += b2f(bias[gn]) + b2f(res[(long)gm * ldc + gn]);
                    long idx = (long)gm * ldc + gn;
                    if (*oflag) ((float*)oout)[idx] = v;
                    else        ((u16*)oout)[idx]   = f2b(v);
                }
            }
        }
    }
}

extern "C" void kernel_launch(void* const* d_in, const int* in_sizes, int n_in,
                              void* d_out, int out_size, void* d_ws, size_t ws_size,
                              hipStream_t stream)
{
    const long MEG = 1L << 20;
    const long KI  = 1024;

    u16* ws = (u16*)d_ws;
    // converted-input region (contiguous, order matches conv_big_k)
    u16* xc    = ws;                    // 4Mi (becomes x2 in-place at GEMM2)
    u16* winC  = ws + 4  * MEG;         // 3Mi
    u16* woutC = ws + 7  * MEG;         // 1Mi
    u16* wfcC  = ws + 8  * MEG;         // 4Mi
    u16* wprjC = ws + 12 * MEG;         // 4Mi
    u16* sm    = ws + 16 * MEG;         // small params, 4Ki-slotted
    u16* ln1g = sm + 0*4*KI, *ln1b = sm + 1*4*KI;
    u16* ln2g = sm + 2*4*KI, *ln2b = sm + 3*4*KI;
    u16* binC = sm + 4*4*KI;
    u16* boutC= sm + 5*4*KI;
    u16* bfcC = sm + 6*4*KI;
    u16* bprjC= sm + 7*4*KI;
    int* flag = (int*)(sm + 8*4*KI);
    u16* slotA = ws + 16 * MEG + 64 * KI;   // 4Mi: h / att / h2
    u16* qB    = slotA + 4  * MEG;      // (B,H,S,DH)
    u16* kB    = slotA + 8  * MEG;      // (B,H,S,DH)
    u16* vT    = slotA + 12 * MEG;      // (B,H,DH,S)
    u16* probs = slotA + 16 * MEG;      // chunk*(H,S,S); reused as act (16Mi)

    // attention batch-chunk size from available workspace
    const long fixed_elems = 32 * MEG + 64 * KI;
    const long avail = (long)(ws_size / 2);
    int chunk = 1;
    if      (avail >= fixed_elems + 64 * MEG) chunk = 4;
    else if (avail >= fixed_elems + 32 * MEG) chunk = 2;

    // 0. detect input dtype; convert everything to bf16 in ws
    detect_k<<<1, 256, 0, stream>>>((const u16*)d_in[0], flag);
    conv_big_k<<<16384, 256, 0, stream>>>(d_in[0], d_in[6], d_in[8], d_in[10],
                                          d_in[12], ws, flag);
    conv_small_k<<<52, 256, 0, stream>>>(d_in[2], d_in[3], d_in[4], d_in[5],
                                         d_in[7], d_in[9], d_in[11], d_in[13],
                                         sm, flag);

    u16* h   = slotA;   // LN1 out
    u16* att = slotA;   // attention out (h dead after QKV)
    u16* h2  = slotA;   // LN2 out (att dead after GEMM2)
    u16* act = probs;

    // 1. LN1
    ln_k<<<4096, 256, 0, stream>>>(xc, ln1g, ln1b, h);
    // 2. QKV projection, routed to q/k/v^T layouts
    gemm_bt<128, 1><<<dim3(24, 32, 1), 256, 0, stream>>>(
        h, winC, nullptr, binC, nullptr, qB, kB, vT,
        4096, 3072, 1024, 1024, 1024, 0, 0, 0, 0, nullptr, nullptr);
    // 3-6. attention, `chunk` batches per sweep
    for (int b0 = 0; b0 < 4; b0 += chunk) {
        gemm_bt<128, 4><<<dim3(8, 8, 16 * chunk), 256, 0, stream>>>(
            qB + b0 * MEG, kB + b0 * MEG, probs, nullptr, nullptr,
            nullptr, nullptr, nullptr,
            1024, 1024, 64, 64, 64, 1024, 65536, 65536, 1048576, nullptr, nullptr);
        softmax_k<<<4096 * chunk, 256, 0, stream>>>(probs);
        gemm_bt<64, 5><<<dim3(1, 8, 16 * chunk), 256, 0, stream>>>(
            probs, vT + b0 * MEG, att + b0 * MEG, nullptr, nullptr,
            nullptr, nullptr, nullptr,
            1024, 64, 1024, 1024, 1024, 1024, 1048576, 65536, 0, nullptr, nullptr);
        mean_k<<<512 * chunk, 256, 0, stream>>>(probs, d_out, 4 * MEG + b0 * MEG, flag);
    }
    // 7. x2 = x + att @ w_out^T + b_out   (in-place over xc: 1 writer/elem)
    gemm_bt<64, 2><<<dim3(16, 32, 1), 256, 0, stream>>>(
        att, woutC, xc, boutC, xc, nullptr, nullptr, nullptr,
        4096, 1024, 1024, 1024, 1024, 1024, 0, 0, 0, nullptr, nullptr);
    // 8. LN2
    ln_k<<<4096, 256, 0, stream>>>(xc, ln2g, ln2b, h2);
    // 9. act = gelu(h2 @ w_fc^T + b_fc)
    gemm_bt<128, 3><<<dim3(32, 32, 1), 256, 0, stream>>>(
        h2, wfcC, act, bfcC, nullptr, nullptr, nullptr, nullptr,
        4096, 4096, 1024, 1024, 1024, 4096, 0, 0, 0, nullptr, nullptr);
    // 10. out = x2 + act @ w_proj^T + b_proj  -> output 0 (flag-adaptive)
    gemm_bt<64, 6><<<dim3(16, 32, 1), 256, 0, stream>>>(
        act, wprjC, nullptr, bprjC, xc, nullptr, nullptr, nullptr,
        4096, 1024, 4096, 4096, 4096, 1024, 0, 0, 0, flag, d_out);
}